// Round 17
// baseline (36.751 us; speedup 1.0000x reference)
//
#include <hip/hip_runtime.h>
#include <stdint.h>

constexpr int Dz = 96, Hy = 160, Wx = 160;
constexpr int NVOX = Dz * Hy * Wx;

#define WAIT_LGKM() do { asm volatile("s_waitcnt lgkmcnt(0)" ::: "memory"); \
                         __builtin_amdgcn_sched_barrier(0); } while (0)

// Wave-autonomous tile: 32d x 8w x 1h per WAVE; 2 waves per 128-thread block.
// Stage 1 is DIRECT register gathers (no LDS staging): per (c,yy) batch of 12
// independent dwordx2 rowpair loads, each wave-instruction spanning a
// contiguous ~53-dword x-range per half (~9 lines). Linearity sums the 3 flow
// stages in registers; wkz factorization shares 4 z-rows across the 4 k's.
__global__ __launch_bounds__(128) void st_fused_kernel(
    const float* __restrict__ src,
    const float* __restrict__ flows,
    const float* __restrict__ rfp,
    float* __restrict__ out)
{
    __shared__ float trbuf[2][292];     // per-wave output transpose only (2.3 KB)
    const int t = threadIdx.x;
    const int lane = t & 63;
    const int v = t >> 6;               // wave id 0..1

    // XCD-aware bijective swizzle (4800 = 8 x 600), then wave-linear tiling.
    const int bid = blockIdx.x;
    const int swz = (bid & 7) * 600 + (bid >> 3);
    const int wid = __builtin_amdgcn_readfirstlane(swz * 2 + v);  // 0..9599
    const int wt = wid % 20;            // w-tile (8 w each)
    const int rest = wid / 20;
    const int dt = rest % 3;            // d-tile (32 d each)
    const int h0 = rest / 3;            // h row 0..159
    const int w0w = wt * 8, d0 = dt * 32;
    const float rf = *rfp;

    const int YB = (159 * h0) / 160;    // y0 row (y1 = YB+1 <= 159)

    // ---- compute mapping: lanes vary d (stage-2 x axis = stride 1) ----
    const int dl = lane & 31;
    const int half = lane >> 5;         // picks w quartet
    const int d = d0 + dl;

    const float xf = (float)(53 * d) * (1.0f / 32.0f);
    const int   x0i = (int)xf;          // 0..157; x0i+1 <= 158 in-bounds
    const float fx  = xf - (float)x0i;
    const float wxa = 1.0f - fx, wxb = fx;

    // z window per half: 4 consecutive absolute rows starting z0a.
    // z0a max = 92 (w=156) -> z0a+3 <= 95: always in-bounds, no clamps.
    int z0a;
    float wkz[4][4];
    {
        int z0k[4]; float wz0k[4], wz1k[4];
#pragma unroll
        for (int k = 0; k < 4; ++k) {
            const int w = w0w + 4 * half + k;
            const float zf = (float)(19 * w) * (1.0f / 32.0f);
            const int zi = (int)zf;
            const float fz = zf - (float)zi;
            z0k[k] = zi; wz0k[k] = 1.0f - fz; wz1k[k] = fz;
        }
        z0a = z0k[0];
#pragma unroll
        for (int r = 0; r < 4; ++r)
#pragma unroll
            for (int k = 0; k < 4; ++k) {
                const int rel = z0k[k] - z0a;            // 0..2
                wkz[r][k] = (rel == r) ? wz0k[k] : ((rel == r - 1) ? wz1k[k] : 0.0f);
            }
    }

    // y-interp: single h, y0i == YB -> 2 terms
    const float fy = (float)h0 * (159.0f / 160.0f) - (float)YB;
    const float wy0 = 1.0f - fy, wy1 = fy;

    // 8 per-thread row pointers (plane 0); other planes via +(s*3+c)*NVOX.
    const float* rp[4][2];
#pragma unroll
    for (int r = 0; r < 4; ++r)
#pragma unroll
        for (int yy = 0; yy < 2; ++yy)
            rp[r][yy] = flows + ((size_t)((z0a + r) * Hy + (YB + yy)) * Wx + x0i);

    float acc[3][4];
#pragma unroll
    for (int c = 0; c < 3; ++c)
#pragma unroll
        for (int k = 0; k < 4; ++k) acc[c][k] = 0.f;

    // ---- stage 1: 6 batches of 12 independent rowpair gathers ----
#pragma unroll
    for (int c = 0; c < 3; ++c) {
#pragma unroll
        for (int yy = 0; yy < 2; ++yy) {
            float2 L[3][4];
#pragma unroll
            for (int s = 0; s < 3; ++s)
#pragma unroll
                for (int r = 0; r < 4; ++r)
                    L[s][r] = *(const float2*)(rp[r][yy] + (size_t)(s * 3 + c) * NVOX);

            float zv0 = 0.f, zv1 = 0.f, zv2 = 0.f, zv3 = 0.f;
#pragma unroll
            for (int r = 0; r < 4; ++r) {
                const float p0 = (L[0][r].x + L[1][r].x) + L[2][r].x;  // stage sum (linearity)
                const float p1 = (L[0][r].y + L[1][r].y) + L[2][r].y;
                const float xv = wxa * p0 + wxb * p1;
                zv0 += wkz[r][0] * xv;
                zv1 += wkz[r][1] * xv;
                zv2 += wkz[r][2] * xv;
                zv3 += wkz[r][3] * xv;
            }
            const float wy = yy ? wy1 : wy0;
            acc[c][0] += wy * zv0;
            acc[c][1] += wy * zv1;
            acc[c][2] += wy * zv2;
            acc[c][3] += wy * zv3;
        }
    }

    // ---- stage 2: row-paired src sampling (zeros mode); results straight to
    // wave-private transpose LDS ----
    float* tr = &trbuf[v][0];           // [32][9] dwords
#pragma unroll
    for (int k = 0; k < 4; ++k) {
        const int w = w0w + 4 * half + k;
        const float f0 = (float)d + acc[0][k] * rf;    // -> x axis of src
        const float f1 = (float)h0 + acc[1][k] * rf;   // -> y axis
        const float f2 = (float)w + acc[2][k] * rf;    // -> z axis

        const float xs = f0 * (159.0f / 95.0f);
        const float ys = f1;
        const float zs = f2 * (95.0f / 159.0f);

        const float xf0 = floorf(xs), yf0 = floorf(ys), zf0 = floorf(zs);
        const float gx = xs - xf0, gy = ys - yf0, gz = zs - zf0;
        const int xi0 = (int)xf0, yi0 = (int)yf0, zi0 = (int)zf0;

        const int xc = min(max(xi0, 0), Wx - 2);
        const bool sx0 = (xi0 == xc);
        const float wx0m = ((unsigned)xi0 < (unsigned)Wx) ? (1.0f - gx) : 0.0f;
        const float wx1m = ((unsigned)(xi0 + 1) < (unsigned)Wx) ? gx : 0.0f;

        const int yc0 = min(max(yi0, 0), Hy - 1);
        const int yc1 = min(max(yi0 + 1, 0), Hy - 1);
        const int zc0 = min(max(zi0, 0), Dz - 1);
        const int zc1 = min(max(zi0 + 1, 0), Dz - 1);
        const float wy0m = ((unsigned)yi0 < (unsigned)Hy) ? (1.0f - gy) : 0.0f;
        const float wy1m = ((unsigned)(yi0 + 1) < (unsigned)Hy) ? gy : 0.0f;
        const float wz0m = ((unsigned)zi0 < (unsigned)Dz) ? (1.0f - gz) : 0.0f;
        const float wz1m = ((unsigned)(zi0 + 1) < (unsigned)Dz) ? gz : 0.0f;

        const float w00 = wz0m * wy0m, w01 = wz0m * wy1m;
        const float w10 = wz1m * wy0m, w11 = wz1m * wy1m;

        float r = 0.0f;
        auto rowadd = [&](int zc, int yc, float wt) {
            const float* p = src + ((size_t)zc * Hy + yc) * Wx + xc;
            const float va = p[0], vb = p[1];
            const float s0 = sx0 ? va : vb;   // value at xi0 (xi0==159 -> vb)
            const float s1 = sx0 ? vb : va;   // value at xi1 (xi0==-1 -> va)
            r += wt * (wx0m * s0 + wx1m * s1);
        };
        rowadd(zc0, yc0, w00);
        rowadd(zc0, yc1, w01);
        rowadd(zc1, yc0, w10);
        rowadd(zc1, yc1, w11);

        tr[dl * 9 + 4 * half + k] = r;
    }
    WAIT_LGKM();

    const int rrow = lane >> 3;         // 0..7
    const int rcol = lane & 7;          // 0..7
#pragma unroll
    for (int m = 0; m < 4; ++m) {
        const int dr = m * 8 + rrow;
        out[((size_t)(d0 + dr) * Hy + h0) * Wx + (w0w + rcol)] =
            tr[dr * 9 + rcol];
    }
}

extern "C" void kernel_launch(void* const* d_in, const int* in_sizes, int n_in,
                              void* d_out, int out_size, void* d_ws, size_t ws_size,
                              hipStream_t stream) {
    const float* src   = (const float*)d_in[0];
    const float* flows = (const float*)d_in[1];
    const float* rfp   = (const float*)d_in[2];
    float* out = (float*)d_out;

    st_fused_kernel<<<dim3(4800), 128, 0, stream>>>(src, flows, rfp, out);
}

// Round 18
// 30.695 us; speedup vs baseline: 1.1973x; 1.1973x over previous
//
#include <hip/hip_runtime.h>
#include <stdint.h>

constexpr int Dz = 96, Hy = 160, Wx = 160;
constexpr int NVOX = Dz * Hy * Wx;

// Wave-autonomous tile: 32d x 8w x 2h per WAVE; 2 waves per 128-thread block.
// Stage-1 footprint per wave: 6 z-rows x 3 y-rows x 56-dword aligned x-pitch.
constexpr int ZW = 6, YW = 3, XP = 56;          // LDS plane: [6][3][56] dwords
constexpr int ROWS = ZW * YW;                   // 18 (z,y) rows
constexpr int NCHUNK = ROWS * 14;               // 252 16B chunks per plane
constexpr int UI = 4;                           // chunk batches (4*64 >= 252)
constexpr int WBUF = UI * 64 * 4;               // 1024 dwords per channel buffer

#define WAIT_LGKM() do { asm volatile("s_waitcnt lgkmcnt(0)" ::: "memory"); \
                         __builtin_amdgcn_sched_barrier(0); } while (0)

__global__ __launch_bounds__(128) void st_fused_kernel(
    const float* __restrict__ src,
    const float* __restrict__ flows,
    const float* __restrict__ rfp,
    float* __restrict__ out)
{
    __shared__ float raw[2][3][WBUF];   // 24 KB: per-wave, per-channel summed buffers
    const int t = threadIdx.x;
    const int v = t >> 6;               // wave id 0..1
    const int lane = t & 63;

    // XCD-aware bijective swizzle (2400 = 8 x 300), then wave-linear tiling
    const int bid = blockIdx.x;
    const int swz = (bid & 7) * 300 + (bid >> 3);
    const int wid = __builtin_amdgcn_readfirstlane(swz * 2 + v);  // 0..4799
    const int wt = wid % 20;            // w-tile (8 w each)
    const int rest = wid / 20;
    const int dt = rest % 3;            // d-tile (32 d each)
    const int hp = rest / 3;            // h-pair 0..79
    const int w0w = wt * 8, d0 = dt * 32, h0 = hp * 2;
    const float rf = *rfp;

    const int Z0w = (19 * w0w) >> 5;
    const int X0 = 53 * dt;             // (53*d0)/32 exact
    const int X0a = X0 & ~3;            // 16B-aligned x origin
    const int YB = (159 * h0) / 160;

    // ---- 4 per-lane chunk addresses (16B each) within plane 0 of stage 0 ----
    const char* ap[UI];
    {
        const char* fb = (const char*)flows + ((size_t)YB * Wx + X0a) * 4;
#pragma unroll
        for (int u = 0; u < UI; ++u) {
            int c = u * 64 + lane;
            if (c >= NCHUNK) c = NCHUNK - 1;     // tail dups (LDS junk, never read)
            int row = c / 14, ch = c - row * 14;
            int zr = row / 3, yr = row - zr * 3;
            ap[u] = fb + ((size_t)((Z0w + zr) * Hy + yr) * Wx) * 4 + ch * 16;
        }
    }

    // ---- stage-1 staging: ALL channels issued up front (36 independent loads);
    // linearity sums the 3 flow stages before interpolation (same sample coords).
    // Compiler software-pipelines; one latency window instead of three.
#pragma unroll
    for (int c = 0; c < 3; ++c) {
        float4* lb4 = (float4*)&raw[v][c][0];
#pragma unroll
        for (int u = 0; u < UI; ++u) {
            const float4 s0 = *(const float4*)(ap[u] + (size_t)(0 + c) * NVOX * 4);
            const float4 s1 = *(const float4*)(ap[u] + (size_t)(3 + c) * NVOX * 4);
            const float4 s2 = *(const float4*)(ap[u] + (size_t)(6 + c) * NVOX * 4);
            float4 s;
            s.x = (s0.x + s1.x) + s2.x;
            s.y = (s0.y + s1.y) + s2.y;
            s.z = (s0.z + s1.z) + s2.z;
            s.w = (s0.w + s1.w) + s2.w;
            lb4[u * 64 + lane] = s;
        }
    }

    // ---- compute mapping: lanes vary d (stage-2 x axis = stride 1) ----
    const int dl = lane & 31;
    const int half = lane >> 5;         // picks w quartet
    const int d = d0 + dl;

    const float xf = (float)(53 * d) * (1.0f / 32.0f);
    const int   x0i = (int)xf;
    const float fx  = xf - (float)x0i;
    const int   xx  = x0i - X0a;        // 0..54
    const float wxa = 1.0f - fx, wxb = fx;

    // z-row factorization: all 4 k's (zz,zz+1) pairs live in 4 consecutive rows.
    int rowoff[4];
    float wkz[4][4];
    {
        int zzk[4]; float wz0k[4], wz1k[4];
#pragma unroll
        for (int k = 0; k < 4; ++k) {
            const int w = w0w + 4 * half + k;
            const float zf = (float)(19 * w) * (1.0f / 32.0f);
            const int z0i = (int)zf;
            const float fz = zf - (float)z0i;
            zzk[k] = z0i - Z0w;         // 0..4, nondecreasing in k
            wz0k[k] = 1.0f - fz; wz1k[k] = fz;
        }
        const int zz0 = zzk[0];
#pragma unroll
        for (int r = 0; r < 4; ++r) {
            rowoff[r] = min(zz0 + r, ZW - 1) * (YW * XP);
#pragma unroll
            for (int k = 0; k < 4; ++k) {
                const int rel = zzk[k] - zz0;            // 0..2
                wkz[r][k] = (rel == r) ? wz0k[k] : ((rel == r - 1) ? wz1k[k] : 0.0f);
            }
        }
    }

    float wyr[2][3];
#pragma unroll
    for (int j = 0; j < 2; ++j) {
        const int h = h0 + j;
        const float yf = (float)h * (159.0f / 160.0f);
        const int y0i = (int)yf;
        const float fy = yf - (float)y0i;
        const int yrel = y0i - YB;      // 0 or 1
        const float a = 1.0f - fy, b = fy;
        wyr[j][0] = (yrel == 0) ? a : 0.0f;
        wyr[j][1] = (yrel == 0) ? b : a;
        wyr[j][2] = (yrel == 0) ? 0.0f : b;
    }

    // 12 row-pair LDS reads per channel (one x-interp per distinct row);
    // sparse wkz scatters rows into the 4 k outputs.
    auto compute = [&](const float* lb, float (&acc)[4][2]) {
#pragma unroll
        for (int yy = 0; yy < 3; ++yy) {
            float zv0 = 0.f, zv1 = 0.f, zv2 = 0.f, zv3 = 0.f;
#pragma unroll
            for (int r = 0; r < 4; ++r) {
                const float* p = lb + rowoff[r] + yy * XP + xx;
                const float xv = wxa * p[0] + wxb * p[1];
                zv0 += wkz[r][0] * xv;
                zv1 += wkz[r][1] * xv;
                zv2 += wkz[r][2] * xv;
                zv3 += wkz[r][3] * xv;
            }
            acc[0][0] += wyr[0][yy] * zv0; acc[0][1] += wyr[1][yy] * zv0;
            acc[1][0] += wyr[0][yy] * zv1; acc[1][1] += wyr[1][yy] * zv1;
            acc[2][0] += wyr[0][yy] * zv2; acc[2][1] += wyr[1][yy] * zv2;
            acc[3][0] += wyr[0][yy] * zv3; acc[3][1] += wyr[1][yy] * zv3;
        }
    };

    float accA[4][2], accB[4][2], accC[4][2];
#pragma unroll
    for (int k = 0; k < 4; ++k)
#pragma unroll
        for (int j = 0; j < 2; ++j) { accA[k][j] = 0.f; accB[k][j] = 0.f; accC[k][j] = 0.f; }

    compute(&raw[v][0][0], accA);
    compute(&raw[v][1][0], accB);
    compute(&raw[v][2][0], accC);

    // ---- stage 2: row-paired src sampling (zeros mode); results straight to
    // wave-private transpose LDS (same-wave ordering) ----
    float* tr = &raw[v][0][0];          // 2 tiles of [32][9] dwords (576 <= 1024)
#pragma unroll
    for (int j = 0; j < 2; ++j) {
        const int h = h0 + j;
#pragma unroll
        for (int k = 0; k < 4; ++k) {
            const int w = w0w + 4 * half + k;
            const float f0 = (float)d + accA[k][j] * rf;   // -> x axis of src
            const float f1 = (float)h + accB[k][j] * rf;   // -> y axis
            const float f2 = (float)w + accC[k][j] * rf;   // -> z axis

            const float xs = f0 * (159.0f / 95.0f);
            const float ys = f1;
            const float zs = f2 * (95.0f / 159.0f);

            const float xf0 = floorf(xs), yf0 = floorf(ys), zf0 = floorf(zs);
            const float gx = xs - xf0, gy = ys - yf0, gz = zs - zf0;
            const int xi0 = (int)xf0, yi0 = (int)yf0, zi0 = (int)zf0;

            const int xc = min(max(xi0, 0), Wx - 2);
            const bool sx0 = (xi0 == xc);
            const float wx0m = ((unsigned)xi0 < (unsigned)Wx) ? (1.0f - gx) : 0.0f;
            const float wx1m = ((unsigned)(xi0 + 1) < (unsigned)Wx) ? gx : 0.0f;

            const int yc0 = min(max(yi0, 0), Hy - 1);
            const int yc1 = min(max(yi0 + 1, 0), Hy - 1);
            const int zc0 = min(max(zi0, 0), Dz - 1);
            const int zc1 = min(max(zi0 + 1, 0), Dz - 1);
            const float wy0m = ((unsigned)yi0 < (unsigned)Hy) ? (1.0f - gy) : 0.0f;
            const float wy1m = ((unsigned)(yi0 + 1) < (unsigned)Hy) ? gy : 0.0f;
            const float wz0m = ((unsigned)zi0 < (unsigned)Dz) ? (1.0f - gz) : 0.0f;
            const float wz1m = ((unsigned)(zi0 + 1) < (unsigned)Dz) ? gz : 0.0f;

            const float w00 = wz0m * wy0m, w01 = wz0m * wy1m;
            const float w10 = wz1m * wy0m, w11 = wz1m * wy1m;

            float r = 0.0f;
            auto rowadd = [&](int zc, int yc, float wt) {
                const float* p = src + ((size_t)zc * Hy + yc) * Wx + xc;
                const float va = p[0], vb = p[1];
                const float s0 = sx0 ? va : vb;   // value at xi0 (xi0==159 -> vb)
                const float s1 = sx0 ? vb : va;   // value at xi1 (xi0==-1 -> va)
                r += wt * (wx0m * s0 + wx1m * s1);
            };
            rowadd(zc0, yc0, w00);
            rowadd(zc0, yc1, w01);
            rowadd(zc1, yc0, w10);
            rowadd(zc1, yc1, w11);

            tr[j * 288 + dl * 9 + 4 * half + k] = r;
        }
    }
    WAIT_LGKM();

    const int rrow = lane >> 3;         // 0..7
    const int rcol = lane & 7;          // 0..7
#pragma unroll
    for (int j = 0; j < 2; ++j)
#pragma unroll
        for (int m = 0; m < 4; ++m) {
            const int dr = m * 8 + rrow;
            out[((size_t)(d0 + dr) * Hy + (h0 + j)) * Wx + (w0w + rcol)] =
                tr[j * 288 + dr * 9 + rcol];
        }
}

extern "C" void kernel_launch(void* const* d_in, const int* in_sizes, int n_in,
                              void* d_out, int out_size, void* d_ws, size_t ws_size,
                              hipStream_t stream) {
    const float* src   = (const float*)d_in[0];
    const float* flows = (const float*)d_in[1];
    const float* rfp   = (const float*)d_in[2];
    float* out = (float*)d_out;

    st_fused_kernel<<<dim3(2400), 128, 0, stream>>>(src, flows, rfp, out);
}